// Round 1
// 1603.850 us; speedup vs baseline: 1.5199x; 1.5199x over previous
//
#include <hip/hip_runtime.h>
#include <hip/hip_bf16.h>

// Problem constants
#define BB 16
#define CIN 7
#define CH 32
#define HH 256
#define WW 256
#define PLANE (HH*WW)                   // 65536
#define YELEMS ((size_t)BB*CH*PLANE)    // 33,554,432 halves = 64 MiB

typedef _Float16 half2v  __attribute__((ext_vector_type(2)));
typedef _Float16 half8   __attribute__((ext_vector_type(8)));
typedef float    float4v __attribute__((ext_vector_type(4)));

// tanh via 1 - 2/(e^{2x}+1): v_rcp_f32 (~1 ulp) instead of the ~10-instr
// IEEE divide the compiler emits for (e-1)/(e+1) without fast-math.
// Error ~1e-7 rel, invisible at f16 storage precision.
__device__ __forceinline__ float fast_tanh(float x) {
    float xc = fminf(fmaxf(x, -15.f), 15.f);
    float e  = __expf(2.f * xc);
    return 1.f - 2.f * __builtin_amdgcn_rcpf(e + 1.f);
}

__device__ __forceinline__ unsigned packh2(float a, float b) {
    half2v h;
    h.x = (_Float16)a;
    h.y = (_Float16)b;
    return __builtin_bit_cast(unsigned, h);
}
__device__ __forceinline__ float2 unpkh2(unsigned u) {
    half2v h = __builtin_bit_cast(half2v, u);
    return make_float2((float)h.x, (float)h.y);
}

// LDS-only barrier (no vmcnt(0) store-ack drain) — proven safe since R6:
// the only cross-wave hazard in the step loop is LDS.
__device__ __forceinline__ void barrier_lds() {
    asm volatile("s_waitcnt lgkmcnt(0)\n\ts_barrier" ::: "memory");
}

// Build shifted B-frag via DPP: result[n] = a[n+KT] for n <= 15-KT,
//                               result[n] = b[n-(16-KT)] for n >= 16-KT.
// row_shl:N -> res[n]=src[n+N]; row_shr:N -> res[n]=src[n-N]; invalid lanes
// keep OLD (bound_ctrl=false). DPP 16-lane rows == n dim. (Fixed in R11.)
template<int KT>
__device__ __forceinline__ unsigned dpp_mix(unsigned a, unsigned b) {
    int t = __builtin_amdgcn_update_dpp(0, (int)b, 0x110 + (16 - KT), 0xF, 0xF, false); // row_shr:16-KT
    int r = __builtin_amdgcn_update_dpp(t, (int)a, 0x100 + KT,        0xF, 0xF, false); // row_shl:KT
    return (unsigned)r;
}
template<int KT>
__device__ __forceinline__ uint4 make_frag(uint4 a, uint4 b) {
    uint4 r;
    r.x = dpp_mix<KT>(a.x, b.x);
    r.y = dpp_mix<KT>(a.y, b.y);
    r.z = dpp_mix<KT>(a.z, b.z);
    r.w = dpp_mix<KT>(a.w, b.w);
    return r;
}

// ---------------------------------------------------------------------------
// Pack scan weights (CH,CH,5) fp32 -> f16 A-fragments (M-permuted, verified
// R11): tile mt, m -> ch_out = 8*(m>>2) + 4*mt + (m&3).
// Also packs w_end (1,32,3,3) -> wEnd[r*32+ci].
__global__ __launch_bounds__(256) void prep_weights(
    unsigned* __restrict__ wA, float* __restrict__ wEnd,
    const float* __restrict__ wu, const float* __restrict__ wd,
    const float* __restrict__ wl, const float* __restrict__ wr,
    const float* __restrict__ we)
{
    int idx = blockIdx.x * 256 + threadIdx.x;
    if (idx < 4 * 2560) {
        int set = idx / 2560;
        int rem = idx % 2560;
        int mt  = rem / 1280;
        int r2  = rem % 1280;
        int kt  = r2 / 256;
        int r3  = r2 % 256;
        int lane = r3 >> 2;
        int jd   = r3 & 3;
        int m    = lane & 15;
        int quad = lane >> 4;
        int ch_out = 8 * (m >> 2) + 4 * mt + (m & 3);   // permuted M
        int ch_in0 = quad * 8 + jd * 2;
        const float* src = (set == 0) ? wu : (set == 1) ? wd : (set == 2) ? wl : wr;
        float a = src[(ch_out * CH + ch_in0) * 5 + kt];
        float b = src[(ch_out * CH + ch_in0 + 1) * 5 + kt];
        wA[idx] = packh2(a, b);
    } else if (idx < 4 * 2560 + 9 * CH) {
        int k  = idx - 4 * 2560;
        int r  = k >> 5;
        int ci = k & 31;
        wEnd[k] = we[ci * 9 + r];
    }
}

// ---------------------------------------------------------------------------
// Init conv: Y[b][h][x][o] = tanh( conv3x3(X) + b ), f16 NHWC output.
__global__ __launch_bounds__(256) void init_conv(
    _Float16* __restrict__ Y, const float* __restrict__ X,
    const float* __restrict__ W, const float* __restrict__ bias)
{
    int bh = blockIdx.x;
    int b  = bh >> 8;
    int h  = bh & 255;
    int x  = threadIdx.x;

    float acc[CH];
    #pragma unroll
    for (int o = 0; o < CH; ++o) acc[o] = bias[o];

    for (int ci = 0; ci < CIN; ++ci) {
        #pragma unroll
        for (int ky = 0; ky < 3; ++ky) {
            int y = h + ky - 1;
            if ((unsigned)y >= (unsigned)HH) continue;
            #pragma unroll
            for (int kx = 0; kx < 3; ++kx) {
                int xx = x + kx - 1;
                float v = ((unsigned)xx < (unsigned)WW)
                          ? X[(((size_t)b * CIN + ci) * HH + y) * WW + xx] : 0.f;
                #pragma unroll
                for (int o = 0; o < CH; ++o)
                    acc[o] = fmaf(v, W[((o * CIN + ci) * 3 + ky) * 3 + kx], acc[o]);
            }
        }
    }
    _Float16* dst = Y + (size_t)b * CH * PLANE + ((size_t)(h * WW + x)) * CH;
    #pragma unroll
    for (int g = 0; g < 4; ++g) {
        uint4 pk;
        pk.x = packh2(fast_tanh(acc[g * 8 + 0]), fast_tanh(acc[g * 8 + 1]));
        pk.y = packh2(fast_tanh(acc[g * 8 + 2]), fast_tanh(acc[g * 8 + 3]));
        pk.z = packh2(fast_tanh(acc[g * 8 + 4]), fast_tanh(acc[g * 8 + 5]));
        pk.w = packh2(fast_tanh(acc[g * 8 + 6]), fast_tanh(acc[g * 8 + 7]));
        *(uint4*)(dst + g * 8) = pk;
    }
}

// ---------------------------------------------------------------------------
// MFMA directional scan, in-place on f16 NHWC Y. One block per image.
// R12: 1024 threads = 16 waves, ONE 16-position tile per wave (was 4 waves
// x 4 tiles). Same per-step totals (32 VMEM, 160 MFMA per block) but now
// 4 waves/SIMD overlap each other's LDS/VMEM/VALU latency — the R11
// structure ran 1 wave/SIMD with a fully exposed per-step latency chain
// (measured 2.1us/step vs ~0.5us of issue work).
// Wave wv owns positions base..base+15, base = wv*16.
//   G0 row = base+n      (positions base-2 .. base+13)
//   G1 row = base+16+n   (positions base+14 .. base+29; only lanes<4 used
//                         via DPP, max row 271 — zero-padded)
// PS/SD in halves. H-scan: PS=32, SD=8192.  W-scan: PS=8192, SD=32.
template<int PS, int SD, bool REV>
__global__ __launch_bounds__(1024) void scan_kernel(
    _Float16* __restrict__ Y, const unsigned* __restrict__ wA,
    const float* __restrict__ bias)
{
    constexpr int P = 40;                     // halves per LDS row (16B mult)
    __shared__ _Float16 S[2][272 * P];        // logical pos p at row p+2;
                                              // rows 258..271 zero pad

    const int tid  = threadIdx.x;
    const int wv   = __builtin_amdgcn_readfirstlane(tid >> 6);   // 0..15
    const int lane = tid & 63;
    const int n    = lane & 15;
    const int quad = lane >> 4;

    // persistent A fragments (weights, M-permuted)
    half8 afrag[2][5];
    #pragma unroll
    for (int mt = 0; mt < 2; ++mt)
        #pragma unroll
        for (int kt = 0; kt < 5; ++kt) {
            uint4 u = *(const uint4*)(wA + (((mt * 5 + kt) * 64 + lane) << 2));
            afrag[mt][kt] = __builtin_bit_cast(half8, u);
        }

    // bias: (mt,r) -> orig ch = 8*quad + 4*mt + r
    float bs[2][4];
    #pragma unroll
    for (int mt = 0; mt < 2; ++mt)
        #pragma unroll
        for (int r = 0; r < 4; ++r)
            bs[mt][r] = bias[8 * quad + 4 * mt + r];

    const int base = wv * 16;                 // this wave's 16 positions
    // gb: half-offset of this lane's 8 channels (16B) at position base+n
    const int gb = (base + n) * PS + 8 * quad;

    _Float16* Yb = Y + (size_t)blockIdx.x * CH * PLANE;

    // zero pad rows {0,1} u {258..271} of both buffers
    for (int it = tid; it < 2 * 16 * P; it += 1024) {
        int bf  = it / (16 * P);
        int rem = it % (16 * P);
        int rr  = rem / P;
        int col = rem % P;
        int row = (rr < 2) ? rr : (256 + rr);
        S[bf][row * P + col] = (_Float16)0.f;
    }

    // initial fill of buf0 with slice sp0: 1024 threads = 256 pos x 4 groups
    {
        const int sp0 = REV ? (HH - 1) : 0;
        int pos = tid & 255;
        int g   = tid >> 8;
        *(uint4*)&S[0][(pos + 2) * P + g * 8] =
            *(const uint4*)(Yb + (size_t)pos * PS + (size_t)sp0 * SD + g * 8);
    }
    __syncthreads();

    auto sp_of = [&](int s) { return REV ? (255 - s) : s; };

    auto body = [&](int s, uint4 &x) {
        const int sp = sp_of(s);
        const _Float16* Sr = S[(s - 1) & 1];
        _Float16*       Sw = S[s & 1];

        // 2 base reads: tap-0 frags of own window and next (b128)
        uint4 G0 = *(const uint4*)(Sr + (base + n) * P + quad * 8);
        uint4 G1 = *(const uint4*)(Sr + (base + 16 + n) * P + quad * 8);

        float4v acc[2];
        acc[0] = float4v{0.f, 0.f, 0.f, 0.f};
        acc[1] = float4v{0.f, 0.f, 0.f, 0.f};

        half8 f0 = __builtin_bit_cast(half8, G0);
        acc[0] = __builtin_amdgcn_mfma_f32_16x16x32_f16(afrag[0][0], f0, acc[0], 0, 0, 0);
        acc[1] = __builtin_amdgcn_mfma_f32_16x16x32_f16(afrag[1][0], f0, acc[1], 0, 0, 0);
        half8 f1 = __builtin_bit_cast(half8, make_frag<1>(G0, G1));
        acc[0] = __builtin_amdgcn_mfma_f32_16x16x32_f16(afrag[0][1], f1, acc[0], 0, 0, 0);
        acc[1] = __builtin_amdgcn_mfma_f32_16x16x32_f16(afrag[1][1], f1, acc[1], 0, 0, 0);
        half8 f2 = __builtin_bit_cast(half8, make_frag<2>(G0, G1));
        acc[0] = __builtin_amdgcn_mfma_f32_16x16x32_f16(afrag[0][2], f2, acc[0], 0, 0, 0);
        acc[1] = __builtin_amdgcn_mfma_f32_16x16x32_f16(afrag[1][2], f2, acc[1], 0, 0, 0);
        half8 f3 = __builtin_bit_cast(half8, make_frag<3>(G0, G1));
        acc[0] = __builtin_amdgcn_mfma_f32_16x16x32_f16(afrag[0][3], f3, acc[0], 0, 0, 0);
        acc[1] = __builtin_amdgcn_mfma_f32_16x16x32_f16(afrag[1][3], f3, acc[1], 0, 0, 0);
        half8 f4 = __builtin_bit_cast(half8, make_frag<4>(G0, G1));
        acc[0] = __builtin_amdgcn_mfma_f32_16x16x32_f16(afrag[0][4], f4, acc[0], 0, 0, 0);
        acc[1] = __builtin_amdgcn_mfma_f32_16x16x32_f16(afrag[1][4], f4, acc[1], 0, 0, 0);

        // unpack f16 X-term: x = 8 ch = [mt0 r0..3][mt1 r0..3]
        float2 p0 = unpkh2(x.x);   // mt0 r0,r1
        float2 p1 = unpkh2(x.y);   // mt0 r2,r3
        float2 p2 = unpkh2(x.z);   // mt1 r0,r1
        float2 p3 = unpkh2(x.w);   // mt1 r2,r3
        float v00 = p0.x + fast_tanh(acc[0][0] + bs[0][0]);
        float v01 = p0.y + fast_tanh(acc[0][1] + bs[0][1]);
        float v02 = p1.x + fast_tanh(acc[0][2] + bs[0][2]);
        float v03 = p1.y + fast_tanh(acc[0][3] + bs[0][3]);
        float v10 = p2.x + fast_tanh(acc[1][0] + bs[1][0]);
        float v11 = p2.y + fast_tanh(acc[1][1] + bs[1][1]);
        float v12 = p3.x + fast_tanh(acc[1][2] + bs[1][2]);
        float v13 = p3.y + fast_tanh(acc[1][3] + bs[1][3]);

        // pack once; identical bits go to global AND LDS
        uint4 pk;
        pk.x = packh2(v00, v01);
        pk.y = packh2(v02, v03);
        pk.z = packh2(v10, v11);
        pk.w = packh2(v12, v13);
        *(uint4*)(Yb + gb + (size_t)sp * SD) = pk;      // fire-and-forget
        *(uint4*)&Sw[(base + n + 2) * P + quad * 8] = pk;

        // prefetch X slice s+2 (1 dwordx4/wave, consumed 2 steps later)
        const int spf = sp_of(s + 2 > 255 ? 255 : s + 2);
        x = *(const uint4*)(Yb + gb + (size_t)spf * SD);

        barrier_lds();
    };

    uint4 xA, xB;
    {
        const int sp1 = sp_of(1), sp2 = sp_of(2);
        xA = *(const uint4*)(Yb + gb + (size_t)sp1 * SD);
        xB = *(const uint4*)(Yb + gb + (size_t)sp2 * SD);
    }

    for (int s = 1; s <= 253; s += 2) {
        body(s,     xA);
        body(s + 1, xB);
    }
    body(255, xA);
}

// ---------------------------------------------------------------------------
// Final conv: sigmoid( conv3x3_{32->1}(Y) + b ), f16 NHWC input.
__global__ __launch_bounds__(256) void final_conv(
    float* __restrict__ out, const _Float16* __restrict__ Y,
    const float* __restrict__ wEnd, const float* __restrict__ bias)
{
    int bh = blockIdx.x;
    int b  = bh >> 8;
    int h  = bh & 255;
    int x  = threadIdx.x;

    const _Float16* Yb = Y + (size_t)b * CH * PLANE;
    float acc = bias[0];
    #pragma unroll
    for (int ky = 0; ky < 3; ++ky) {
        int y = h + ky - 1;
        if ((unsigned)y >= (unsigned)HH) continue;
        #pragma unroll
        for (int kx = 0; kx < 3; ++kx) {
            int xx = x + kx - 1;
            if ((unsigned)xx >= (unsigned)WW) continue;
            const _Float16* p = Yb + (size_t)(y * WW + xx) * CH;
            const float* wp = wEnd + (ky * 3 + kx) * CH;
            #pragma unroll
            for (int cg = 0; cg < 4; ++cg) {
                uint2 u = *(const uint2*)(p + cg * 8);
                float2 a0 = unpkh2(u.x);
                float2 a1 = unpkh2(u.y);
                acc += a0.x * wp[cg * 8 + 0] + a0.y * wp[cg * 8 + 1]
                     + a1.x * wp[cg * 8 + 2] + a1.y * wp[cg * 8 + 3];
                uint2 u2 = *(const uint2*)(p + cg * 8 + 4);
                float2 a2 = unpkh2(u2.x);
                float2 a3 = unpkh2(u2.y);
                acc += a2.x * wp[cg * 8 + 4] + a2.y * wp[cg * 8 + 5]
                     + a3.x * wp[cg * 8 + 6] + a3.y * wp[cg * 8 + 7];
            }
        }
    }
    float sg = 1.f / (1.f + __expf(-acc));
    out[((size_t)b * HH + h) * WW + x] = sg;
}

// ---------------------------------------------------------------------------
extern "C" void kernel_launch(void* const* d_in, const int* in_sizes, int n_in,
                              void* d_out, int out_size, void* d_ws, size_t ws_size,
                              hipStream_t stream)
{
    const float* X      = (const float*)d_in[0];
    const float* w_init = (const float*)d_in[1];
    const float* b_init = (const float*)d_in[2];
    const float* w_u    = (const float*)d_in[3];
    const float* b_u    = (const float*)d_in[4];
    const float* w_d    = (const float*)d_in[5];
    const float* b_d    = (const float*)d_in[6];
    const float* w_l    = (const float*)d_in[7];
    const float* b_l    = (const float*)d_in[8];
    const float* w_r    = (const float*)d_in[9];
    const float* b_r    = (const float*)d_in[10];
    const float* w_end  = (const float*)d_in[11];
    const float* b_end  = (const float*)d_in[12];
    float* out = (float*)d_out;

    _Float16* Y    = (_Float16*)d_ws;           // 64 MiB f16 NHWC state
    unsigned* wA   = (unsigned*)(Y + YELEMS);   // 10240 dwords f16 A-fragments
    float*    wEnd = (float*)(wA + 10240);      // 288 floats packed w_end

    prep_weights<<<dim3(42), dim3(256), 0, stream>>>(wA, wEnd, w_u, w_d, w_l, w_r, w_end);
    init_conv<<<dim3(BB * HH), dim3(256), 0, stream>>>(Y, X, w_init, b_init);

    // up: axis=H (s=h, pos=w), reverse:  PS=32, SD=8192 (halves)
    scan_kernel<32, 8192, true ><<<dim3(BB), dim3(1024), 0, stream>>>(Y, wA + 0 * 2560, b_u);
    // down: axis=H, forward
    scan_kernel<32, 8192, false><<<dim3(BB), dim3(1024), 0, stream>>>(Y, wA + 1 * 2560, b_d);
    // left: axis=W (s=w, pos=h), reverse: PS=8192, SD=32
    scan_kernel<8192, 32, true ><<<dim3(BB), dim3(1024), 0, stream>>>(Y, wA + 2 * 2560, b_l);
    // right: axis=W, forward
    scan_kernel<8192, 32, false><<<dim3(BB), dim3(1024), 0, stream>>>(Y, wA + 3 * 2560, b_r);

    final_conv<<<dim3(BB * HH), dim3(256), 0, stream>>>(out, Y, wEnd, b_end);
}

// Round 2
// 1228.374 us; speedup vs baseline: 1.9845x; 1.3057x over previous
//
#include <hip/hip_runtime.h>
#include <hip/hip_bf16.h>

// Problem constants
#define BB 16
#define CIN 7
#define CH 32
#define HH 256
#define WW 256
#define PLANE (HH*WW)                   // 65536
#define YELEMS ((size_t)BB*CH*PLANE)    // 33,554,432 halves = 64 MiB

typedef _Float16 half2v  __attribute__((ext_vector_type(2)));
typedef _Float16 half8   __attribute__((ext_vector_type(8)));
typedef float    float4v __attribute__((ext_vector_type(4)));

// tanh via 1 - 2/(e^{2x}+1). No clamp needed: exp->inf gives rcp->0 -> +1,
// exp->0 gives -1; saturation is correct at both ends, no NaN path.
// 3 VALU + 2 trans ops.
__device__ __forceinline__ float fast_tanh(float x) {
    float e = __expf(2.f * x);
    return 1.f - 2.f * __builtin_amdgcn_rcpf(e + 1.f);
}

__device__ __forceinline__ unsigned packh2(float a, float b) {
    half2v h;
    h.x = (_Float16)a;
    h.y = (_Float16)b;
    return __builtin_bit_cast(unsigned, h);
}
__device__ __forceinline__ float2 unpkh2(unsigned u) {
    half2v h = __builtin_bit_cast(half2v, u);
    return make_float2((float)h.x, (float)h.y);
}

// LDS-only barrier (no vmcnt(0) store-ack drain) — proven safe since R6:
// the only cross-wave hazard in the step loop is LDS.
__device__ __forceinline__ void barrier_lds() {
    asm volatile("s_waitcnt lgkmcnt(0)\n\ts_barrier" ::: "memory");
}

// ---------------------------------------------------------------------------
// Pack scan weights (CH,CH,5) fp32 -> f16 A-fragments (M-permuted, verified
// R11): tile mt, m -> ch_out = 8*(m>>2) + 4*mt + (m&3).
// Also packs w_end (1,32,3,3) -> wEnd[r*32+ci].
__global__ __launch_bounds__(256) void prep_weights(
    unsigned* __restrict__ wA, float* __restrict__ wEnd,
    const float* __restrict__ wu, const float* __restrict__ wd,
    const float* __restrict__ wl, const float* __restrict__ wr,
    const float* __restrict__ we)
{
    int idx = blockIdx.x * 256 + threadIdx.x;
    if (idx < 4 * 2560) {
        int set = idx / 2560;
        int rem = idx % 2560;
        int mt  = rem / 1280;
        int r2  = rem % 1280;
        int kt  = r2 / 256;
        int r3  = r2 % 256;
        int lane = r3 >> 2;
        int jd   = r3 & 3;
        int m    = lane & 15;
        int quad = lane >> 4;
        int ch_out = 8 * (m >> 2) + 4 * mt + (m & 3);   // permuted M
        int ch_in0 = quad * 8 + jd * 2;
        const float* src = (set == 0) ? wu : (set == 1) ? wd : (set == 2) ? wl : wr;
        float a = src[(ch_out * CH + ch_in0) * 5 + kt];
        float b = src[(ch_out * CH + ch_in0 + 1) * 5 + kt];
        wA[idx] = packh2(a, b);
    } else if (idx < 4 * 2560 + 9 * CH) {
        int k  = idx - 4 * 2560;
        int r  = k >> 5;
        int ci = k & 31;
        wEnd[k] = we[ci * 9 + r];
    }
}

// ---------------------------------------------------------------------------
// Init conv: Y[b][h][x][o] = tanh( conv3x3(X) + b ), f16 NHWC output.
__global__ __launch_bounds__(256) void init_conv(
    _Float16* __restrict__ Y, const float* __restrict__ X,
    const float* __restrict__ W, const float* __restrict__ bias)
{
    int bh = blockIdx.x;
    int b  = bh >> 8;
    int h  = bh & 255;
    int x  = threadIdx.x;

    float acc[CH];
    #pragma unroll
    for (int o = 0; o < CH; ++o) acc[o] = bias[o];

    for (int ci = 0; ci < CIN; ++ci) {
        #pragma unroll
        for (int ky = 0; ky < 3; ++ky) {
            int y = h + ky - 1;
            if ((unsigned)y >= (unsigned)HH) continue;
            #pragma unroll
            for (int kx = 0; kx < 3; ++kx) {
                int xx = x + kx - 1;
                float v = ((unsigned)xx < (unsigned)WW)
                          ? X[(((size_t)b * CIN + ci) * HH + y) * WW + xx] : 0.f;
                #pragma unroll
                for (int o = 0; o < CH; ++o)
                    acc[o] = fmaf(v, W[((o * CIN + ci) * 3 + ky) * 3 + kx], acc[o]);
            }
        }
    }
    _Float16* dst = Y + (size_t)b * CH * PLANE + ((size_t)(h * WW + x)) * CH;
    #pragma unroll
    for (int g = 0; g < 4; ++g) {
        uint4 pk;
        pk.x = packh2(fast_tanh(acc[g * 8 + 0]), fast_tanh(acc[g * 8 + 1]));
        pk.y = packh2(fast_tanh(acc[g * 8 + 2]), fast_tanh(acc[g * 8 + 3]));
        pk.z = packh2(fast_tanh(acc[g * 8 + 4]), fast_tanh(acc[g * 8 + 5]));
        pk.w = packh2(fast_tanh(acc[g * 8 + 6]), fast_tanh(acc[g * 8 + 7]));
        *(uint4*)(dst + g * 8) = pk;
    }
}

// ---------------------------------------------------------------------------
// MFMA directional scan, in-place on f16 NHWC Y. One block per image.
// R13: VALU diet on the R12 16-wave structure.
//  - Tap fragments read DIRECTLY from LDS (5x ds_read_b128 at +kt*80B)
//    instead of 2 reads + 32 DPP mix ops/lane/step. Bit-exact: tap-kt col n
//    = row base+n+kt, rows up to 259 are zero-padded.
//  - Bias preloaded into the MFMA C-init (saves 8 adds/lane/step).
//  - tanh clamp dropped (saturation exact without it).
// Wave wv owns positions base..base+15, base = wv*16.
// PS/SD in halves. H-scan: PS=32, SD=8192.  W-scan: PS=8192, SD=32.
template<int PS, int SD, bool REV>
__global__ __launch_bounds__(1024) void scan_kernel(
    _Float16* __restrict__ Y, const unsigned* __restrict__ wA,
    const float* __restrict__ bias)
{
    constexpr int P = 40;                     // halves per LDS row (16B mult)
    __shared__ _Float16 S[2][272 * P];        // logical pos p at row p+2;
                                              // rows 258..271 zero pad

    const int tid  = threadIdx.x;
    const int wv   = __builtin_amdgcn_readfirstlane(tid >> 6);   // 0..15
    const int lane = tid & 63;
    const int n    = lane & 15;
    const int quad = lane >> 4;

    // persistent A fragments (weights, M-permuted)
    half8 afrag[2][5];
    #pragma unroll
    for (int mt = 0; mt < 2; ++mt)
        #pragma unroll
        for (int kt = 0; kt < 5; ++kt) {
            uint4 u = *(const uint4*)(wA + (((mt * 5 + kt) * 64 + lane) << 2));
            afrag[mt][kt] = __builtin_bit_cast(half8, u);
        }

    // bias as MFMA C-init: acc reg r at lane(n,quad) is row m=quad*4+r,
    // permuted ch_out = 8*quad + 4*mt + r.
    float4v bias0, bias1;
    #pragma unroll
    for (int r = 0; r < 4; ++r) {
        bias0[r] = bias[8 * quad + r];
        bias1[r] = bias[8 * quad + 4 + r];
    }

    const int base = wv * 16;                 // this wave's 16 positions
    // gb: half-offset of this lane's 8 channels (16B) at position base+n
    const int gb = (base + n) * PS + 8 * quad;

    _Float16* Yb = Y + (size_t)blockIdx.x * CH * PLANE;

    // zero pad rows {0,1} u {258..271} of both buffers
    for (int it = tid; it < 2 * 16 * P; it += 1024) {
        int bf  = it / (16 * P);
        int rem = it % (16 * P);
        int rr  = rem / P;
        int col = rem % P;
        int row = (rr < 2) ? rr : (256 + rr);
        S[bf][row * P + col] = (_Float16)0.f;
    }

    // initial fill of buf0 with slice sp0: 1024 threads = 256 pos x 4 groups
    {
        const int sp0 = REV ? (HH - 1) : 0;
        int pos = tid & 255;
        int g   = tid >> 8;
        *(uint4*)&S[0][(pos + 2) * P + g * 8] =
            *(const uint4*)(Yb + (size_t)pos * PS + (size_t)sp0 * SD + g * 8);
    }
    __syncthreads();

    auto sp_of = [&](int s) { return REV ? (255 - s) : s; };

    auto body = [&](int s, uint4 &x) {
        const int sp = sp_of(s);
        const _Float16* Sr = S[(s - 1) & 1];
        _Float16*       Sw = S[s & 1];

        // 5 tap reads: f_kt = rows base+n+kt (b128, +kt*80B imm offset).
        // 2-way bank aliasing (n vs n+8) only — free.
        const _Float16* rp = Sr + (base + n) * P + quad * 8;
        uint4 G[5];
        #pragma unroll
        for (int kt = 0; kt < 5; ++kt)
            G[kt] = *(const uint4*)(rp + kt * P);

        float4v acc0 = bias0;
        float4v acc1 = bias1;
        #pragma unroll
        for (int kt = 0; kt < 5; ++kt) {
            half8 f = __builtin_bit_cast(half8, G[kt]);
            acc0 = __builtin_amdgcn_mfma_f32_16x16x32_f16(afrag[0][kt], f, acc0, 0, 0, 0);
            acc1 = __builtin_amdgcn_mfma_f32_16x16x32_f16(afrag[1][kt], f, acc1, 0, 0, 0);
        }

        // unpack f16 X-term: x = 8 ch = [mt0 r0..3][mt1 r0..3]
        float2 p0 = unpkh2(x.x);   // mt0 r0,r1
        float2 p1 = unpkh2(x.y);   // mt0 r2,r3
        float2 p2 = unpkh2(x.z);   // mt1 r0,r1
        float2 p3 = unpkh2(x.w);   // mt1 r2,r3
        float v00 = p0.x + fast_tanh(acc0[0]);
        float v01 = p0.y + fast_tanh(acc0[1]);
        float v02 = p1.x + fast_tanh(acc0[2]);
        float v03 = p1.y + fast_tanh(acc0[3]);
        float v10 = p2.x + fast_tanh(acc1[0]);
        float v11 = p2.y + fast_tanh(acc1[1]);
        float v12 = p3.x + fast_tanh(acc1[2]);
        float v13 = p3.y + fast_tanh(acc1[3]);

        // pack once; identical bits go to global AND LDS
        uint4 pk;
        pk.x = packh2(v00, v01);
        pk.y = packh2(v02, v03);
        pk.z = packh2(v10, v11);
        pk.w = packh2(v12, v13);
        *(uint4*)(Yb + gb + (size_t)sp * SD) = pk;      // fire-and-forget
        *(uint4*)&Sw[(base + n + 2) * P + quad * 8] = pk;

        // prefetch X slice s+2 (1 dwordx4/wave, consumed 2 steps later)
        const int spf = sp_of(s + 2 > 255 ? 255 : s + 2);
        x = *(const uint4*)(Yb + gb + (size_t)spf * SD);

        barrier_lds();
    };

    uint4 xA, xB;
    {
        const int sp1 = sp_of(1), sp2 = sp_of(2);
        xA = *(const uint4*)(Yb + gb + (size_t)sp1 * SD);
        xB = *(const uint4*)(Yb + gb + (size_t)sp2 * SD);
    }

    for (int s = 1; s <= 253; s += 2) {
        body(s,     xA);
        body(s + 1, xB);
    }
    body(255, xA);
}

// ---------------------------------------------------------------------------
// Final conv: sigmoid( conv3x3_{32->1}(Y) + b ), f16 NHWC input.
__global__ __launch_bounds__(256) void final_conv(
    float* __restrict__ out, const _Float16* __restrict__ Y,
    const float* __restrict__ wEnd, const float* __restrict__ bias)
{
    int bh = blockIdx.x;
    int b  = bh >> 8;
    int h  = bh & 255;
    int x  = threadIdx.x;

    const _Float16* Yb = Y + (size_t)b * CH * PLANE;
    float acc = bias[0];
    #pragma unroll
    for (int ky = 0; ky < 3; ++ky) {
        int y = h + ky - 1;
        if ((unsigned)y >= (unsigned)HH) continue;
        #pragma unroll
        for (int kx = 0; kx < 3; ++kx) {
            int xx = x + kx - 1;
            if ((unsigned)xx >= (unsigned)WW) continue;
            const _Float16* p = Yb + (size_t)(y * WW + xx) * CH;
            const float* wp = wEnd + (ky * 3 + kx) * CH;
            #pragma unroll
            for (int cg = 0; cg < 4; ++cg) {
                uint2 u = *(const uint2*)(p + cg * 8);
                float2 a0 = unpkh2(u.x);
                float2 a1 = unpkh2(u.y);
                acc += a0.x * wp[cg * 8 + 0] + a0.y * wp[cg * 8 + 1]
                     + a1.x * wp[cg * 8 + 2] + a1.y * wp[cg * 8 + 3];
                uint2 u2 = *(const uint2*)(p + cg * 8 + 4);
                float2 a2 = unpkh2(u2.x);
                float2 a3 = unpkh2(u2.y);
                acc += a2.x * wp[cg * 8 + 4] + a2.y * wp[cg * 8 + 5]
                     + a3.x * wp[cg * 8 + 6] + a3.y * wp[cg * 8 + 7];
            }
        }
    }
    float sg = 1.f / (1.f + __expf(-acc));
    out[((size_t)b * HH + h) * WW + x] = sg;
}

// ---------------------------------------------------------------------------
extern "C" void kernel_launch(void* const* d_in, const int* in_sizes, int n_in,
                              void* d_out, int out_size, void* d_ws, size_t ws_size,
                              hipStream_t stream)
{
    const float* X      = (const float*)d_in[0];
    const float* w_init = (const float*)d_in[1];
    const float* b_init = (const float*)d_in[2];
    const float* w_u    = (const float*)d_in[3];
    const float* b_u    = (const float*)d_in[4];
    const float* w_d    = (const float*)d_in[5];
    const float* b_d    = (const float*)d_in[6];
    const float* w_l    = (const float*)d_in[7];
    const float* b_l    = (const float*)d_in[8];
    const float* w_r    = (const float*)d_in[9];
    const float* b_r    = (const float*)d_in[10];
    const float* w_end  = (const float*)d_in[11];
    const float* b_end  = (const float*)d_in[12];
    float* out = (float*)d_out;

    _Float16* Y    = (_Float16*)d_ws;           // 64 MiB f16 NHWC state
    unsigned* wA   = (unsigned*)(Y + YELEMS);   // 10240 dwords f16 A-fragments
    float*    wEnd = (float*)(wA + 10240);      // 288 floats packed w_end

    prep_weights<<<dim3(42), dim3(256), 0, stream>>>(wA, wEnd, w_u, w_d, w_l, w_r, w_end);
    init_conv<<<dim3(BB * HH), dim3(256), 0, stream>>>(Y, X, w_init, b_init);

    // up: axis=H (s=h, pos=w), reverse:  PS=32, SD=8192 (halves)
    scan_kernel<32, 8192, true ><<<dim3(BB), dim3(1024), 0, stream>>>(Y, wA + 0 * 2560, b_u);
    // down: axis=H, forward
    scan_kernel<32, 8192, false><<<dim3(BB), dim3(1024), 0, stream>>>(Y, wA + 1 * 2560, b_d);
    // left: axis=W (s=w, pos=h), reverse: PS=8192, SD=32
    scan_kernel<8192, 32, true ><<<dim3(BB), dim3(1024), 0, stream>>>(Y, wA + 2 * 2560, b_l);
    // right: axis=W, forward
    scan_kernel<8192, 32, false><<<dim3(BB), dim3(1024), 0, stream>>>(Y, wA + 3 * 2560, b_r);

    final_conv<<<dim3(BB * HH), dim3(256), 0, stream>>>(out, Y, wEnd, b_end);
}